// Round 1
// baseline (676.095 us; speedup 1.0000x reference)
//
#include <hip/hip_runtime.h>
#include <hip/hip_bf16.h>

#define B_ 1024
#define L_ 2048
#define C_ 32
#define O_ 2048

typedef short bf16x8 __attribute__((ext_vector_type(8)));
typedef float f32x4 __attribute__((ext_vector_type(4)));

__device__ __forceinline__ unsigned int f2bf(float f) {
    union { float f; unsigned int u; } v; v.f = f;
    unsigned int r = v.u + (0x7fffu + ((v.u >> 16) & 1u));
    return r >> 16;
}

__device__ __forceinline__ void async16(const void* g, const void* l) {
    __builtin_amdgcn_global_load_lds(
        (const __attribute__((address_space(1))) unsigned int*)g,
        (__attribute__((address_space(3))) unsigned int*)l, 16, 0, 0);
}

// ---------------- fused pre-pass ----------------
// blocks [0, 8192):   x (B,L,C) fp32 -> xT (B,C,L) bf16, LDS-staged coalesced transpose
// blocks [8192, 10240): W_pos fp32 -> bf16
__global__ __launch_bounds__(256) void k_prep(const float* __restrict__ x,
                                              unsigned short* __restrict__ xT,
                                              const float* __restrict__ wp,
                                              unsigned short* __restrict__ wpb) {
    const int t = threadIdx.x;
    if (blockIdx.x < 8192) {
        // LDS tile: [c=32][dcol=128] dwords; dword dcol holds bf16 pair (l=2*dcol, 2*dcol+1).
        // Quad-XOR swizzle keyed on (c>>2)&7: write 2-way (free), read conflict-free.
        __shared__ unsigned int lds[32 * 128];
        const int b  = blockIdx.x >> 3;
        const int l0 = (blockIdx.x & 7) << 8;        // 256-l chunk
        const int c0 = (t & 7) << 2;                 // channel quad 0,4,..,28
        const int lr = (t >> 3) << 1;                // even l within 64-l group
        const float* src = x + (size_t)b * (L_ * C_) + (size_t)l0 * C_;
#pragma unroll
        for (int i = 0; i < 4; ++i) {
            const int l = i * 64 + lr;
            // fully coalesced: each 128B row segment consumed by 8 lanes x 16B
            const float4 e = *(const float4*)(src + (size_t)l * C_ + c0);
            const float4 o = *(const float4*)(src + (size_t)(l + 1) * C_ + c0);
            const int dcol = l >> 1;                 // i*32 + (t>>3)
            const float ef[4] = {e.x, e.y, e.z, e.w};
            const float of[4] = {o.x, o.y, o.z, o.w};
#pragma unroll
            for (int j = 0; j < 4; ++j) {
                const int c = c0 + j;
                const unsigned int pk = f2bf(ef[j]) | (f2bf(of[j]) << 16);
                lds[c * 128 + (dcol ^ (((c >> 2) & 7) << 2))] = pk;
            }
        }
        __syncthreads();
        // write-out: 4 uint4/thread; each wave writes two full 512B rows -> coalesced
        unsigned short* dst = xT + (size_t)b * (C_ * L_) + l0;
#pragma unroll
        for (int i = 0; i < 4; ++i) {
            const int f  = i * 256 + t;
            const int c  = f >> 5;                   // output row (channel)
            const int lq = f & 31;                   // uint4 index within row
            const int k  = (c >> 2) & 7;
            const unsigned int* s = &lds[c * 128 + ((lq ^ k) << 2)];
            uint4 q; q.x = s[0]; q.y = s[1]; q.z = s[2]; q.w = s[3];
            *(uint4*)(dst + (size_t)c * L_ + lq * 8) = q;
        }
    } else {
        const size_t i = ((size_t)(blockIdx.x - 8192) * 256 + t) * 8;
        float4 v0 = *(const float4*)(wp + i);
        float4 v1 = *(const float4*)(wp + i + 4);
        uint4 q;
        q.x = f2bf(v0.x) | (f2bf(v0.y) << 16);
        q.y = f2bf(v0.z) | (f2bf(v0.w) << 16);
        q.z = f2bf(v1.x) | (f2bf(v1.y) << 16);
        q.w = f2bf(v1.z) | (f2bf(v1.w) << 16);
        *(uint4*)(wpb + i) = q;
    }
}

// ---------------- main fused GEMM ----------------
// A = xT (32768 x 2048 bf16 row-major, rows r = b*32+c), B^T = W_pos bf16 (2048 x 2048)
// epilogue: out[b,o] = sum_c Wc[o,c] * t[(b,c),o]
__global__ __launch_bounds__(256) void k_gemm(const unsigned short* __restrict__ A,
                                              const unsigned short* __restrict__ Wp,
                                              const float* __restrict__ Wc,
                                              float* __restrict__ out) {
    __shared__ unsigned short As[128 * 64];
    __shared__ unsigned short Bs[128 * 64];
    const int mt = blockIdx.x >> 4;               // 256 m-tiles
    const int nt = blockIdx.x & 15;               // 16 n-tiles
    const int t = threadIdx.x;
    const int lane = t & 63;
    const int w = t >> 6;
    const int rowBase = mt << 7;
    const int colBase = nt << 7;

    const int srow = w * 8 + (lane >> 3);         // staging row within 32-row chunk
    const int kg = lane & 7;                      // dest kgroup (8 bf16 each)
    const int kgsA = (kg ^ (srow & 7)) * 8;       // swizzled source kgroup offset (elems)

    const unsigned short* pa[4];
    const unsigned short* pb[4];
#pragma unroll
    for (int i = 0; i < 4; ++i) {
        pa[i] = A  + (size_t)(rowBase + i * 32 + srow) * 2048 + kgsA;
        pb[i] = Wp + (size_t)(colBase + i * 32 + srow) * 2048 + kgsA;
    }
    char* lA = (char*)As + w * 1024;
    char* lB = (char*)Bs + w * 1024;

    f32x4 acc[4][4] = {};

    const int wm = w >> 1, wn = w & 1;
    const int quad = lane >> 4, c16 = lane & 15;

    for (int kt = 0; kt < 32; ++kt) {
        const int k0 = kt * 64;
#pragma unroll
        for (int i = 0; i < 4; ++i) {
            async16(pa[i] + k0, lA + i * 4096);
            async16(pb[i] + k0, lB + i * 4096);
        }
        __syncthreads();                          // drains vmcnt + barrier
#pragma unroll
        for (int ks = 0; ks < 2; ++ks) {
            bf16x8 af[4], bfr[4];
#pragma unroll
            for (int mi = 0; mi < 4; ++mi) {
                int r = wm * 64 + mi * 16 + c16;
                af[mi] = *(const bf16x8*)((const char*)As + r * 128 + (((ks << 2) | quad) ^ (r & 7)) * 16);
                int cl = wn * 64 + mi * 16 + c16;
                bfr[mi] = *(const bf16x8*)((const char*)Bs + cl * 128 + (((ks << 2) | quad) ^ (cl & 7)) * 16);
            }
#pragma unroll
            for (int mi = 0; mi < 4; ++mi)
#pragma unroll
                for (int ni = 0; ni < 4; ++ni)
                    acc[mi][ni] = __builtin_amdgcn_mfma_f32_16x16x32_bf16(af[mi], bfr[ni], acc[mi][ni], 0, 0, 0);
        }
        __syncthreads();                          // protect LDS before next stage
    }

    // ---- epilogue: weighted c-reduction, write out[b, o] ----
    const int ob = colBase + wn * 64;
#pragma unroll
    for (int j = 0; j < 2; ++j) {                 // 2 b's per wave
        const int bg = (mt << 2) + (wm << 1) + j;
#pragma unroll
        for (int ni = 0; ni < 4; ++ni) {
            const int o = ob + ni * 16 + c16;
            const f32x4 w0 = *(const f32x4*)(Wc + o * 32 + quad * 4);        // c = quad*4..+3
            const f32x4 w1 = *(const f32x4*)(Wc + o * 32 + 16 + quad * 4);   // c = 16+quad*4..+3
            const f32x4 aA = acc[2 * j][ni];
            const f32x4 aB = acc[2 * j + 1][ni];
            float s = aA[0] * w0[0] + aA[1] * w0[1] + aA[2] * w0[2] + aA[3] * w0[3]
                    + aB[0] * w1[0] + aB[1] * w1[1] + aB[2] * w1[2] + aB[3] * w1[3];
            s += __shfl_xor(s, 16, 64);
            s += __shfl_xor(s, 32, 64);
            if (quad == 0) out[(size_t)bg * O_ + o] = s;
        }
    }
}

// ---------------- fallback (only if ws too small): fp32 VALU, slow but correct ----------------
__global__ __launch_bounds__(256) void k_fallback(const float* __restrict__ x,
                                                  const float* __restrict__ wpos,
                                                  const float* __restrict__ wchan,
                                                  float* __restrict__ out) {
    __shared__ float xs[128 * 32];
    const int b = blockIdx.x >> 3;
    const int o = ((blockIdx.x & 7) << 8) + threadIdx.x;
    float wc[32];
#pragma unroll
    for (int c = 0; c < 32; ++c) wc[c] = wchan[o * 32 + c];
    float acc = 0.f;
    for (int l0 = 0; l0 < 2048; l0 += 128) {
        __syncthreads();
#pragma unroll
        for (int i = 0; i < 16; ++i) {
            int f = i * 256 + threadIdx.x;
            xs[f] = x[(size_t)b * 65536 + (size_t)l0 * 32 + f];
        }
        __syncthreads();
        for (int l = 0; l < 128; ++l) {
            float wp = wpos[(size_t)o * 2048 + l0 + l];
            float s = 0.f;
#pragma unroll
            for (int c = 0; c < 32; ++c) s += xs[l * 32 + c] * wc[c];
            acc += wp * s;
        }
    }
    out[(size_t)b * 2048 + o] = acc;
}

extern "C" void kernel_launch(void* const* d_in, const int* in_sizes, int n_in,
                              void* d_out, int out_size, void* d_ws, size_t ws_size,
                              hipStream_t stream) {
    const float* x     = (const float*)d_in[0];
    const float* wpos  = (const float*)d_in[1];
    const float* wchan = (const float*)d_in[2];
    float* out = (float*)d_out;

    const size_t xT_bytes = (size_t)B_ * C_ * L_ * 2;   // 128 MiB
    const size_t wp_bytes = (size_t)O_ * L_ * 2;        // 8 MiB

    if (ws_size >= xT_bytes + wp_bytes) {
        unsigned short* xT  = (unsigned short*)d_ws;
        unsigned short* wpb = (unsigned short*)((char*)d_ws + xT_bytes);
        k_prep<<<8192 + 2048, 256, 0, stream>>>(x, xT, wpos, wpb);
        k_gemm<<<(B_ * C_ / 128) * (O_ / 128), 256, 0, stream>>>(xT, wpb, wchan, out);
    } else {
        k_fallback<<<B_ * 8, 256, 0, stream>>>(x, wpos, wchan, out);
    }
}

// Round 2
// 628.876 us; speedup vs baseline: 1.0751x; 1.0751x over previous
//
#include <hip/hip_runtime.h>
#include <hip/hip_bf16.h>

#define B_ 1024
#define L_ 2048
#define C_ 32
#define O_ 2048

typedef short bf16x8 __attribute__((ext_vector_type(8)));
typedef float f32x4 __attribute__((ext_vector_type(4)));

__device__ __forceinline__ unsigned int f2bf(float f) {
    union { float f; unsigned int u; } v; v.f = f;
    unsigned int r = v.u + (0x7fffu + ((v.u >> 16) & 1u));
    return r >> 16;
}

__device__ __forceinline__ void async16(const void* g, const void* l) {
    __builtin_amdgcn_global_load_lds(
        (const __attribute__((address_space(1))) unsigned int*)g,
        (__attribute__((address_space(3))) unsigned int*)l, 16, 0, 0);
}

// ---------------- fused pre-pass ----------------
// blocks [0, 8192):   x (B,L,C) fp32 -> xT (B,C,L) bf16, LDS-staged coalesced transpose
// blocks [8192, 10240): W_pos fp32 -> bf16
__global__ __launch_bounds__(256) void k_prep(const float* __restrict__ x,
                                              unsigned short* __restrict__ xT,
                                              const float* __restrict__ wp,
                                              unsigned short* __restrict__ wpb) {
    const int t = threadIdx.x;
    if (blockIdx.x < 8192) {
        __shared__ unsigned int lds[32 * 128];
        const int b  = blockIdx.x >> 3;
        const int l0 = (blockIdx.x & 7) << 8;        // 256-l chunk
        const int c0 = (t & 7) << 2;                 // channel quad 0,4,..,28
        const int lr = (t >> 3) << 1;                // even l within 64-l group
        const float* src = x + (size_t)b * (L_ * C_) + (size_t)l0 * C_;
#pragma unroll
        for (int i = 0; i < 4; ++i) {
            const int l = i * 64 + lr;
            const float4 e = *(const float4*)(src + (size_t)l * C_ + c0);
            const float4 o = *(const float4*)(src + (size_t)(l + 1) * C_ + c0);
            const int dcol = l >> 1;
            const float ef[4] = {e.x, e.y, e.z, e.w};
            const float of[4] = {o.x, o.y, o.z, o.w};
#pragma unroll
            for (int j = 0; j < 4; ++j) {
                const int c = c0 + j;
                const unsigned int pk = f2bf(ef[j]) | (f2bf(of[j]) << 16);
                lds[c * 128 + (dcol ^ (((c >> 2) & 7) << 2))] = pk;
            }
        }
        __syncthreads();
        unsigned short* dst = xT + (size_t)b * (C_ * L_) + l0;
#pragma unroll
        for (int i = 0; i < 4; ++i) {
            const int f  = i * 256 + t;
            const int c  = f >> 5;
            const int lq = f & 31;
            const int k  = (c >> 2) & 7;
            const unsigned int* s = &lds[c * 128 + ((lq ^ k) << 2)];
            uint4 q; q.x = s[0]; q.y = s[1]; q.z = s[2]; q.w = s[3];
            *(uint4*)(dst + (size_t)c * L_ + lq * 8) = q;
        }
    } else {
        const size_t i = ((size_t)(blockIdx.x - 8192) * 256 + t) * 8;
        float4 v0 = *(const float4*)(wp + i);
        float4 v1 = *(const float4*)(wp + i + 4);
        uint4 q;
        q.x = f2bf(v0.x) | (f2bf(v0.y) << 16);
        q.y = f2bf(v0.z) | (f2bf(v0.w) << 16);
        q.z = f2bf(v1.x) | (f2bf(v1.y) << 16);
        q.w = f2bf(v1.z) | (f2bf(v1.w) << 16);
        *(uint4*)(wpb + i) = q;
    }
}

// ---------------- main fused GEMM: 256x256 tile, BK=64, 8-phase counted-vmcnt ----------------
// A = xT (32768 x 2048 bf16, rows r = b*32+c), B^T = Wp (2048 x 2048 bf16)
// LDS halves = 16-row-block parity; quadrants = (mi-parity x ni-parity).
// Stage ledger (iter I, tiles 2I->buf0, 2I+1->buf1):
//  ph1: A1(2I+1)  ph2: A0(2I+2)  ph3: B0(2I+2)  ph4: B1(2I+2)+vmcnt(6)
//  ph5: A1(2I+2)  ph6: A0(2I+3)  ph7: B0(2I+3)  ph8: B1(2I+3)+vmcnt(6)
// Every stage >=1 barrier after its region's last read; every read guarded by a
// vmcnt(6)+barrier 3 half-tiles upstream.

#define BAR() __builtin_amdgcn_s_barrier()
#define LGKM0() do { asm volatile("s_waitcnt lgkmcnt(0)" ::: "memory"); __builtin_amdgcn_sched_barrier(0); } while (0)
#define VMW(N) asm volatile("s_waitcnt vmcnt(" #N ")" ::: "memory")
#define PRIO1() __builtin_amdgcn_s_setprio(1)
#define PRIO0() __builtin_amdgcn_s_setprio(0)

#define STG_A(buf, h, tk) do { \
    async16(A + offA + (size_t)(tk) * 64 + (h) * 32768,         (char*)As + (buf) * 32768 + (h) * 16384 + stgo); \
    async16(A + offA + (size_t)(tk) * 64 + (h) * 32768 + 16384, (char*)As + (buf) * 32768 + (h) * 16384 + stgo + 1024); } while (0)
#define STG_B(buf, h, tk) do { \
    async16(Wp + offB + (size_t)(tk) * 64 + (h) * 32768,         (char*)Bs + (buf) * 32768 + (h) * 16384 + stgo); \
    async16(Wp + offB + (size_t)(tk) * 64 + (h) * 32768 + 16384, (char*)Bs + (buf) * 32768 + (h) * 16384 + stgo + 1024); } while (0)

#define RD_A(buf, am) do { \
    _Pragma("unroll") for (int p_ = 0; p_ < 4; ++p_) { \
        const char* ap_ = (const char*)As + (buf) * 32768 + (am) * 16384 + rowA[p_]; \
        af[p_][0] = *(const bf16x8*)(ap_ + kof0); \
        af[p_][1] = *(const bf16x8*)(ap_ + kof1); } } while (0)
#define RD_B(buf, bn, dst) do { \
    _Pragma("unroll") for (int q_ = 0; q_ < 2; ++q_) { \
        const char* bp_ = (const char*)Bs + (buf) * 32768 + (bn) * 16384 + rowB[q_]; \
        dst[q_][0] = *(const bf16x8*)(bp_ + kof0); \
        dst[q_][1] = *(const bf16x8*)(bp_ + kof1); } } while (0)

#define MM(am, bn, bsrc) do { \
    _Pragma("unroll") for (int p_ = 0; p_ < 4; ++p_) \
    _Pragma("unroll") for (int q_ = 0; q_ < 2; ++q_) \
    _Pragma("unroll") for (int ks_ = 0; ks_ < 2; ++ks_) \
        acc[2 * p_ + (am)][2 * q_ + (bn)] = __builtin_amdgcn_mfma_f32_16x16x32_bf16( \
            af[p_][ks_], bsrc[q_][ks_], acc[2 * p_ + (am)][2 * q_ + (bn)], 0, 0, 0); } while (0)

__global__ __launch_bounds__(512, 2) void k_gemm(const unsigned short* __restrict__ A,
                                                 const unsigned short* __restrict__ Wp,
                                                 const float* __restrict__ Wc,
                                                 float* __restrict__ out) {
    __shared__ unsigned short As[2][2][8192];   // [buf][half][128 rows x 64 k]
    __shared__ unsigned short Bs[2][2][8192];
    const int mt = blockIdx.x >> 3;             // 128 m-tiles
    const int nt = blockIdx.x & 7;              // 8 n-tiles
    const int t = threadIdx.x, lane = t & 63, w = t >> 6;
    const int wm = w >> 2, wn = w & 3;
    const int quad = lane >> 4, c16 = lane & 15;

    // staging addressing: thread covers rows gr = base + w*32 + h*16 + j*8 + s_, kgroup kg^s_
    const int s_ = lane >> 3, kg = lane & 7;
    const int kgs = (kg ^ s_) << 3;             // swizzled kgroup, elements
    const size_t offA = (size_t)((mt << 8) + (w << 5) + s_) * 2048 + kgs;
    const size_t offB = (size_t)((nt << 8) + (w << 5) + s_) * 2048 + kgs;
    const int stgo = w << 11;                   // LDS byte base within half

    // read addressing
    int rowA[4], rowB[2];
#pragma unroll
    for (int p = 0; p < 4; ++p) rowA[p] = ((((wm << 2) + p) << 4) | c16) << 7;
#pragma unroll
    for (int q = 0; q < 2; ++q) rowB[q] = ((((wn << 1) + q) << 4) | c16) << 7;
    const int sw = c16 & 7;
    const int kof0 = (quad ^ sw) << 4;
    const int kof1 = ((4 + quad) ^ sw) << 4;

    bf16x8 af[4][2], bfe[2][2], bfo[2][2];
    f32x4 acc[8][4] = {};

    // prologue: tile0 (4 halves) then tile1 (3 halves); tile0 guaranteed by vmcnt(6)
    STG_A(0, 0, 0); STG_B(0, 0, 0); STG_B(0, 1, 0); STG_A(0, 1, 0);
    STG_A(1, 0, 1); STG_B(1, 0, 1); STG_B(1, 1, 1);
    VMW(6); BAR();

    for (int I = 0; I < 15; ++I) {
        const int t1 = 2 * I + 1, t2 = 2 * I + 2, t3 = 2 * I + 3;
        RD_A(0, 0); RD_B(0, 0, bfe); STG_A(1, 1, t1); BAR(); LGKM0(); PRIO1(); MM(0, 0, bfe); PRIO0(); BAR();
        RD_B(0, 1, bfo);             STG_A(0, 0, t2); BAR(); LGKM0(); PRIO1(); MM(0, 1, bfo); PRIO0(); BAR();
        RD_A(0, 1);                  STG_B(0, 0, t2); BAR(); LGKM0(); PRIO1(); MM(1, 0, bfe); PRIO0(); BAR();
                                     STG_B(0, 1, t2); VMW(6); BAR();  PRIO1(); MM(1, 1, bfo); PRIO0(); BAR();
        RD_A(1, 0); RD_B(1, 0, bfe); STG_A(0, 1, t2); BAR(); LGKM0(); PRIO1(); MM(0, 0, bfe); PRIO0(); BAR();
        RD_B(1, 1, bfo);             STG_A(1, 0, t3); BAR(); LGKM0(); PRIO1(); MM(0, 1, bfo); PRIO0(); BAR();
        RD_A(1, 1);                  STG_B(1, 0, t3); BAR(); LGKM0(); PRIO1(); MM(1, 0, bfe); PRIO0(); BAR();
                                     STG_B(1, 1, t3); VMW(6); BAR();  PRIO1(); MM(1, 1, bfo); PRIO0(); BAR();
    }
    // tail: tiles 30 (buf0), 31 (buf1); A1(31) staged at ph1; vmcnt(0) before buf1 reads
    RD_A(0, 0); RD_B(0, 0, bfe); STG_A(1, 1, 31); BAR(); LGKM0(); PRIO1(); MM(0, 0, bfe); PRIO0(); BAR();
    RD_B(0, 1, bfo);                              BAR(); LGKM0(); PRIO1(); MM(0, 1, bfo); PRIO0(); BAR();
    RD_A(0, 1);                                   BAR(); LGKM0(); PRIO1(); MM(1, 0, bfe); PRIO0(); BAR();
                                  VMW(0);         BAR();          PRIO1(); MM(1, 1, bfo); PRIO0(); BAR();
    RD_A(1, 0); RD_B(1, 0, bfe);                  BAR(); LGKM0(); PRIO1(); MM(0, 0, bfe); PRIO0(); BAR();
    RD_B(1, 1, bfo);                              BAR(); LGKM0(); PRIO1(); MM(0, 1, bfo); PRIO0(); BAR();
    RD_A(1, 1);                                   BAR(); LGKM0(); PRIO1(); MM(1, 0, bfe); PRIO0(); BAR();
                                                                  PRIO1(); MM(1, 1, bfo); PRIO0();

    // ---- epilogue: weighted c-reduction, out[b,o] = sum_c Wc[o,c]*u[(b,c),o] ----
    // row R = mt*256 + wm*128 + mi*16 + quad*4 + reg  ->  b = mt*8+wm*4+p (mi=2p+par),
    // c = par*16 + quad*4 + reg  (in-wave across quad via shfl_xor 16/32)
    const int colW = (nt << 8) + (wn << 6);
#pragma unroll
    for (int p = 0; p < 4; ++p) {
        const int bg = (mt << 3) + (wm << 2) + p;
#pragma unroll
        for (int ni = 0; ni < 4; ++ni) {
            const int o = colW + (ni << 4) + c16;
            const f32x4 w0 = *(const f32x4*)(Wc + o * 32 + quad * 4);
            const f32x4 w1 = *(const f32x4*)(Wc + o * 32 + 16 + quad * 4);
            const f32x4 aA = acc[2 * p][ni];
            const f32x4 aB = acc[2 * p + 1][ni];
            float sv = aA[0] * w0[0] + aA[1] * w0[1] + aA[2] * w0[2] + aA[3] * w0[3]
                     + aB[0] * w1[0] + aB[1] * w1[1] + aB[2] * w1[2] + aB[3] * w1[3];
            sv += __shfl_xor(sv, 16, 64);
            sv += __shfl_xor(sv, 32, 64);
            if (quad == 0) out[(size_t)bg * O_ + o] = sv;
        }
    }
}

// ---------------- fallback (only if ws too small): fp32 VALU, slow but correct ----------------
__global__ __launch_bounds__(256) void k_fallback(const float* __restrict__ x,
                                                  const float* __restrict__ wpos,
                                                  const float* __restrict__ wchan,
                                                  float* __restrict__ out) {
    __shared__ float xs[128 * 32];
    const int b = blockIdx.x >> 3;
    const int o = ((blockIdx.x & 7) << 8) + threadIdx.x;
    float wc[32];
#pragma unroll
    for (int c = 0; c < 32; ++c) wc[c] = wchan[o * 32 + c];
    float acc = 0.f;
    for (int l0 = 0; l0 < 2048; l0 += 128) {
        __syncthreads();
#pragma unroll
        for (int i = 0; i < 16; ++i) {
            int f = i * 256 + threadIdx.x;
            xs[f] = x[(size_t)b * 65536 + (size_t)l0 * 32 + f];
        }
        __syncthreads();
        for (int l = 0; l < 128; ++l) {
            float wp = wpos[(size_t)o * 2048 + l0 + l];
            float s = 0.f;
#pragma unroll
            for (int c = 0; c < 32; ++c) s += xs[l * 32 + c] * wc[c];
            acc += wp * s;
        }
    }
    out[(size_t)b * 2048 + o] = acc;
}

extern "C" void kernel_launch(void* const* d_in, const int* in_sizes, int n_in,
                              void* d_out, int out_size, void* d_ws, size_t ws_size,
                              hipStream_t stream) {
    const float* x     = (const float*)d_in[0];
    const float* wpos  = (const float*)d_in[1];
    const float* wchan = (const float*)d_in[2];
    float* out = (float*)d_out;

    const size_t xT_bytes = (size_t)B_ * C_ * L_ * 2;   // 128 MiB
    const size_t wp_bytes = (size_t)O_ * L_ * 2;        // 8 MiB

    if (ws_size >= xT_bytes + wp_bytes) {
        unsigned short* xT  = (unsigned short*)d_ws;
        unsigned short* wpb = (unsigned short*)((char*)d_ws + xT_bytes);
        k_prep<<<8192 + 2048, 256, 0, stream>>>(x, xT, wpos, wpb);
        k_gemm<<<(B_ * C_ / 256) * (O_ / 256), 512, 0, stream>>>(xT, wpb, wchan, out);
    } else {
        k_fallback<<<B_ * 8, 256, 0, stream>>>(x, wpos, wchan, out);
    }
}